// Round 1
// 316.982 us; speedup vs baseline: 1.1219x; 1.1219x over previous
//
#include <hip/hip_runtime.h>

typedef unsigned short u16;
typedef unsigned int u32;
typedef __bf16 bf16x8 __attribute__((ext_vector_type(8)));
typedef float f32x4 __attribute__((ext_vector_type(4)));

#define B_  4
#define T_  2048
#define C_  1024
#define NH_ 16
#define D_  64
#define M_  (B_*T_)          // 8192
#define N_QKV (3*C_)         // 3072

#define ATTN_BLOCKS 1024     // one block per item, 4 blocks/CU (32KB LDS)

// raw barrier + static waitcnt (no vmcnt(0) drain -- keeps prefetch in flight)
#define BARRIER()  __asm__ __volatile__("s_barrier" ::: "memory")
#define WAIT_VM4() __asm__ __volatile__("s_waitcnt vmcnt(4)" ::: "memory")
#define WAIT_VM0() __asm__ __volatile__("s_waitcnt vmcnt(0)" ::: "memory")

// async global->LDS, 16B per lane. LDS dest = wave-uniform base + lane*16
__device__ __forceinline__ void async_copy16(void* lds, const void* gptr) {
  __builtin_amdgcn_global_load_lds(
      (const __attribute__((address_space(1))) u32*)gptr,
      (__attribute__((address_space(3))) u32*)(u32)(uintptr_t)lds,
      16, 0, 0);
}

// RNE float -> bf16 bits
__device__ __forceinline__ u16 f2bf(float f) {
  union { float f; unsigned u; } c; c.f = f;
  unsigned u = c.u;
  unsigned r = (u + 0x7fffu + ((u >> 16) & 1u)) >> 16;
  return (u16)r;
}

// ---------------- elementwise fp32 -> bf16 ----------------
__global__ __launch_bounds__(256) void conv_bf16(const float* __restrict__ in,
                                                 u16* __restrict__ out, int n) {
  int i = (blockIdx.x * 256 + threadIdx.x) * 4;
  if (i < n) {
    float4 f = *reinterpret_cast<const float4*>(in + i);
    u16 o[4] = { f2bf(f.x), f2bf(f.y), f2bf(f.z), f2bf(f.w) };
    *reinterpret_cast<uint2*>(out + i) = *reinterpret_cast<uint2*>(o);
  }
}

// ---------------- transpose fp32 [K][N] -> bf16 [N][K] ----------------
__global__ __launch_bounds__(256) void transpose_bf16(const float* __restrict__ in,
                                                      u16* __restrict__ out,
                                                      int K, int N) {
  __shared__ float tile[32][33];
  int bi = blockIdx.y;
  int bj = blockIdx.x;
  int tx = threadIdx.x & 31;
  int ty = threadIdx.x >> 5;
#pragma unroll
  for (int i = 0; i < 4; ++i) {
    int row = ty + i * 8;
    tile[row][tx] = in[(bi * 32 + row) * N + bj * 32 + tx];
  }
  __syncthreads();
#pragma unroll
  for (int i = 0; i < 4; ++i) {
    int row = ty + i * 8;
    out[(bj * 32 + row) * K + bi * 32 + tx] = f2bf(tile[tx][row]);
  }
}

// ---------------- QKV GEMM (R5 BK=32 m97 structure) ----------------
__global__ __launch_bounds__(256) void gemm_qkv(const u16* __restrict__ A,
                                                const u16* __restrict__ Bt,
                                                const float* __restrict__ b_attn,
                                                const float* __restrict__ bQ,
                                                const float* __restrict__ bK,
                                                u16* __restrict__ qo,
                                                u16* __restrict__ ko,
                                                u16* __restrict__ vo) {
  const int K = C_;
  int bm = blockIdx.y, bn = blockIdx.x;
  int tid = threadIdx.x;
  int wid = tid >> 6, lane = tid & 63;
  int lm = lane & 15, lq = lane >> 4;
  int wm = (wid >> 1) * 64, wn = (wid & 1) * 64;

  __shared__ u16 As[128 * 32];
  __shared__ u16 Bs[128 * 32];

  f32x4 acc[4][4];
#pragma unroll
  for (int i = 0; i < 4; ++i)
#pragma unroll
    for (int j = 0; j < 4; ++j) acc[i][j] = (f32x4){0.f, 0.f, 0.f, 0.f};

  const u16* Ab = A + (bm * 128) * K;
  const u16* Bb = Bt + (bn * 128) * K;
  int srow = lane >> 2;
  int scol = (lane & 3) * 8;

  for (int k0 = 0; k0 < K; k0 += 32) {
    __syncthreads();
#pragma unroll
    for (int j = 0; j < 2; ++j) {
      int c = wid * 2 + j;
      int row = c * 16 + srow;
      async_copy16(&As[c * 512], Ab + row * K + k0 + scol);
      async_copy16(&Bs[c * 512], Bb + row * K + k0 + scol);
    }
    __syncthreads();
    bf16x8 af[4], bf[4];
#pragma unroll
    for (int mt = 0; mt < 4; ++mt)
      af[mt] = *reinterpret_cast<const bf16x8*>(&As[(wm + mt * 16 + lm) * 32 + lq * 8]);
#pragma unroll
    for (int nt = 0; nt < 4; ++nt)
      bf[nt] = *reinterpret_cast<const bf16x8*>(&Bs[(wn + nt * 16 + lm) * 32 + lq * 8]);
#pragma unroll
    for (int mt = 0; mt < 4; ++mt)
#pragma unroll
      for (int nt = 0; nt < 4; ++nt)
        acc[mt][nt] = __builtin_amdgcn_mfma_f32_16x16x32_bf16(af[mt], bf[nt], acc[mt][nt], 0, 0, 0);
  }

  const float qscale = 0.18033688011112042f;  // 1/sqrt(64) * log2(e)
#pragma unroll
  for (int mt = 0; mt < 4; ++mt) {
#pragma unroll
    for (int nt = 0; nt < 4; ++nt) {
#pragma unroll
      for (int r = 0; r < 4; ++r) {
        int m = bm * 128 + wm + mt * 16 + lq * 4 + r;
        int n = bn * 128 + wn + nt * 16 + lm;
        float val = acc[mt][nt][r] + b_attn[n];
        int sel = n >> 10;
        int c = n & 1023;
        int h = c >> 6;
        int d = c & 63;
        int b = m >> 11;
        int t = m & 2047;
        if (sel == 0)      qo[(((b * NH_ + h) * T_) + t) * D_ + d] = f2bf((val + bQ[c]) * qscale);
        else if (sel == 1) ko[(((b * NH_ + h) * T_) + t) * D_ + d] = f2bf(val + bK[c]);
        else               vo[(((b * NH_ + h) * D_) + d) * T_ + t] = f2bf(val);  // transposed
      }
    }
  }
}

// ---------------- Flash attention ----------------
// 1024 blocks, one (bh, 128-row q-tile) item each, all resident at 4 blocks/CU
// (32 KB LDS). Static LPT-balanced mapping: blocks {c, c+256, c+512, c+768}
// (same CU under round-robin dispatch) get qt {15-a, 8+a, 7-a, a} with a=c&7
// -> exactly 68 k-tile iters per CU; critical path = longest item = 32 iters.
// P never touches LDS: the MFMA k-slot->key mapping is permuted so the
// in-register S layout (lane lq holds keys kt*16+lq*4+r) IS the PV B-operand;
// V is read with matching per-lane b64 offsets. Pipeline per iter unchanged:
//   wait vmcnt(4) [own share of tile kbi landed]; s_barrier
//   S MFMA + softmax (in-reg) + PV MFMA from buf kbi&1
//   s_barrier ; stage tile kbi+2 (clamped -> static vmcnt counts)
__global__ __launch_bounds__(256, 4) void attn_kernel(const u16* __restrict__ q,
                                                      const u16* __restrict__ k,
                                                      const u16* __restrict__ vt,
                                                      u16* __restrict__ y) {
  int tid = threadIdx.x;
  int w = tid >> 6, lane = tid & 63;
  int lm = lane & 15, lq = lane >> 4;

  __shared__ u16 Ks[2][64 * 64];   // [buf][key][d swizzled]    16 KB
  __shared__ u16 Vs[2][64 * 64];   // [buf][d][key swizzled]    16 KB

  int srow = lane >> 3;            // staging row within 8-row chunk
  int sg   = (lane & 7) ^ srow;    // swizzled 16B col-group

  // static balanced mapping (LPT): see header comment
  int idx = blockIdx.x;
  int c8 = idx & 255, jq = idx >> 8;
  int a = c8 & 7, gq = c8 >> 3;
  int qt, bh;
  if (jq == 0)      { qt = 15 - a; bh = gq; }
  else if (jq == 1) { qt = 8 + a;  bh = 32 + gq; }
  else if (jq == 2) { qt = 7 - a;  bh = gq; }
  else              { qt = a;      bh = 32 + gq; }

  int b = bh >> 4, h = bh & 15;
  const int klast = 2 * qt + 1;
  const int qrow0 = qt * 128 + w * 32;

  const u16* qb = q + ((size_t)bh * T_ + qrow0) * D_;
  const u16* kb = k + (size_t)bh * T_ * D_;
  const u16* vb = vt + (size_t)bh * D_ * T_;   // [d][t]

  // wave w stages chunks {2w, 2w+1} of each 8 KB tile (2 DMA instr/tile)
  auto stage_K = [&](int buf, int kbi) {
    const u16* gb = kb + (size_t)(kbi * 64) * 64;
#pragma unroll
    for (int j = 0; j < 2; ++j) {
      int c = w * 2 + j;
      async_copy16(&Ks[buf][c * 512], gb + (c * 8 + srow) * 64 + sg * 8);
    }
  };
  auto stage_V = [&](int buf, int kbi) {
    const u16* gb = vb + kbi * 64;
#pragma unroll
    for (int j = 0; j < 2; ++j) {
      int c = w * 2 + j;
      async_copy16(&Vs[buf][c * 512], gb + (size_t)(c * 8 + srow) * T_ + sg * 8);
    }
  };

  // Q as B-operand: lane n=q=lm, k=d (pre-scaled by 1/sqrt(D)*log2e)
  bf16x8 bq[2][2];
#pragma unroll
  for (int qt2 = 0; qt2 < 2; ++qt2) {
    const u16* qp = qb + (qt2 * 16 + lm) * D_ + lq * 8;
    bq[qt2][0] = *reinterpret_cast<const bf16x8*>(qp);
    bq[qt2][1] = *reinterpret_cast<const bf16x8*>(qp + 32);
  }

  f32x4 o[4][2];
#pragma unroll
  for (int dt = 0; dt < 4; ++dt)
#pragma unroll
    for (int qt2 = 0; qt2 < 2; ++qt2) o[dt][qt2] = (f32x4){0.f, 0.f, 0.f, 0.f};
  float mprev[2] = {-1e30f, -1e30f}, lsum[2] = {0.f, 0.f};

  // prologue: tiles 0 and 1 (8 DMA per wave outstanding)
  stage_K(0, 0); stage_V(0, 0);
  stage_K(1, 1); stage_V(1, 1);

  for (int kbi = 0; kbi <= klast; ++kbi) {
    int buf = kbi & 1;
    WAIT_VM4();                  // own share of tile kbi landed (tile kbi+1 flying)
    BARRIER();                   // all waves' shares landed

    // K frags: row=key=kt*16+lm, swizzled col-group g^(lm&7)
    bf16x8 kf[4][2];
#pragma unroll
    for (int kt = 0; kt < 4; ++kt) {
      const u16* base = &Ks[buf][(kt * 16 + lm) * 64];
      kf[kt][0] = *reinterpret_cast<const bf16x8*>(base + ((lq ^ (lm & 7)) * 8));
      kf[kt][1] = *reinterpret_cast<const bf16x8*>(base + (((4 + lq) ^ (lm & 7)) * 8));
    }

    // S^T[key][q]: lane (q=lm, lq) element r of s[kt] -> key kt*16+lq*4+r
    f32x4 s[4][2];
#pragma unroll
    for (int kt = 0; kt < 4; ++kt)
#pragma unroll
      for (int qt2 = 0; qt2 < 2; ++qt2) {
        f32x4 z = (f32x4){0.f, 0.f, 0.f, 0.f};
        z = __builtin_amdgcn_mfma_f32_16x16x32_bf16(kf[kt][0], bq[qt2][0], z, 0, 0, 0);
        z = __builtin_amdgcn_mfma_f32_16x16x32_bf16(kf[kt][1], bq[qt2][1], z, 0, 0, 0);
        s[kt][qt2] = z;
      }

    bool maskt = (kbi * 64 + 63 > qrow0);
    bf16x8 pb[2][2];             // P as PV B-operand, natural key order
#pragma unroll
    for (int qt2 = 0; qt2 < 2; ++qt2) {
      int qg = qrow0 + qt2 * 16 + lm;
      if (maskt) {
#pragma unroll
        for (int kt = 0; kt < 4; ++kt)
#pragma unroll
          for (int r = 0; r < 4; ++r) {
            int key = kbi * 64 + kt * 16 + lq * 4 + r;
            if (key > qg) s[kt][qt2][r] = -1e30f;
          }
      }
      // max as depth-4 tree (latency) instead of 15-deep chain
      float mx[4];
#pragma unroll
      for (int kt = 0; kt < 4; ++kt)
        mx[kt] = fmaxf(fmaxf(s[kt][qt2][0], s[kt][qt2][1]),
                       fmaxf(s[kt][qt2][2], s[kt][qt2][3]));
      float mval = fmaxf(fmaxf(mx[0], mx[1]), fmaxf(mx[2], mx[3]));
      mval = fmaxf(mval, __shfl_xor(mval, 16));
      mval = fmaxf(mval, __shfl_xor(mval, 32));
      float mold = mprev[qt2];
      float mnew = fmaxf(mold, mval);
      unsigned long long upd = __ballot(mval > mold);
      if (upd) {
        float alpha = __builtin_exp2f(mold - mnew);
        lsum[qt2] *= alpha;
#pragma unroll
        for (int dt = 0; dt < 4; ++dt) o[dt][qt2] *= alpha;
        mprev[qt2] = mnew;
      }
      float rs = 0.f;
      unsigned pw[8];
#pragma unroll
      for (int kt = 0; kt < 4; ++kt) {
        unsigned pu[4];
#pragma unroll
        for (int r = 0; r < 4; ++r) {
          float p = __builtin_exp2f(s[kt][qt2][r] - mnew);
          rs += p;
          union { float f; unsigned u; } cc; cc.f = p;
          pu[r] = cc.u;
        }
        pw[kt * 2]     = __builtin_amdgcn_perm(pu[1], pu[0], 0x07060302u);
        pw[kt * 2 + 1] = __builtin_amdgcn_perm(pu[3], pu[2], 0x07060302u);
      }
      rs += __shfl_xor(rs, 16);
      rs += __shfl_xor(rs, 32);
      lsum[qt2] += rs;
      union { unsigned u[4]; bf16x8 v; } b0, b1;
#pragma unroll
      for (int t = 0; t < 4; ++t) { b0.u[t] = pw[t]; b1.u[t] = pw[4 + t]; }
      pb[qt2][0] = b0.v;   // keys kt=0,1: slot (lq,j) -> key (j>>2)*16 + lq*4 + (j&3)
      pb[qt2][1] = b1.v;   // keys kt=2,3
    }

    // PV with the SAME permuted k-slot->key map on the V (A) operand:
    // slot (lq, j<4) -> key kt_lo*16 + lq*4 + j ; (lq, j>=4) -> +16.
    // V^T row d: keys lq*4.. and 16+lq*4.. are b64 halves of 16B groups
    // g0=lq>>1 (+2/+4/+6), XOR-deswizzled by row&7.
    {
      int r7 = lm & 7;
      int h4 = (lq & 1) * 4;
      int g0 = lq >> 1;
#pragma unroll
      for (int dt = 0; dt < 4; ++dt) {
        const u16* vbase = &Vs[buf][(dt * 16 + lm) * 64];
        union { unsigned long long qd[2]; bf16x8 v; } t0, t1;
        t0.qd[0] = *reinterpret_cast<const unsigned long long*>(vbase + ((g0 ^ r7) * 8) + h4);
        t0.qd[1] = *reinterpret_cast<const unsigned long long*>(vbase + (((g0 + 2) ^ r7) * 8) + h4);
        t1.qd[0] = *reinterpret_cast<const unsigned long long*>(vbase + (((g0 + 4) ^ r7) * 8) + h4);
        t1.qd[1] = *reinterpret_cast<const unsigned long long*>(vbase + (((g0 + 6) ^ r7) * 8) + h4);
#pragma unroll
        for (int qt2 = 0; qt2 < 2; ++qt2) {
          o[dt][qt2] = __builtin_amdgcn_mfma_f32_16x16x32_bf16(t0.v, pb[qt2][0], o[dt][qt2], 0, 0, 0);
          o[dt][qt2] = __builtin_amdgcn_mfma_f32_16x16x32_bf16(t1.v, pb[qt2][1], o[dt][qt2], 0, 0, 0);
        }
      }
    }

    BARRIER();                   // all waves done reading buf before overwrite
    int nk = (kbi + 2 <= klast) ? kbi + 2 : klast;  // clamp: keeps counts static
    stage_K(buf, nk); stage_V(buf, nk);
  }

  WAIT_VM0();  // drain tail prefetches before LDS is freed at endpgm

  // write y[b][t=q][h][d]; O^T C-layout: col=q=lm, row=d=dt*16+lq*4+r -> 8B stores
#pragma unroll
  for (int qt2 = 0; qt2 < 2; ++qt2) {
    float inv = 1.f / lsum[qt2];
    int qg = qrow0 + qt2 * 16 + lm;
#pragma unroll
    for (int dt = 0; dt < 4; ++dt) {
      u16 wb[4];
#pragma unroll
      for (int r = 0; r < 4; ++r) wb[r] = f2bf(o[dt][qt2][r] * inv);
      int d = dt * 16 + lq * 4;
      *reinterpret_cast<uint2*>(&y[((size_t)(b * T_ + qg) * NH_ + h) * D_ + d]) =
          *reinterpret_cast<uint2*>(wb);
    }
  }
}

// ---------------- Proj GEMM (R5 BK=32 m97 structure) ----------------
__global__ __launch_bounds__(256) void gemm_proj(const u16* __restrict__ A,
                                                 const u16* __restrict__ Bt,
                                                 const float* __restrict__ b_proj,
                                                 float* __restrict__ out) {
  const int K = C_, N = C_;
  int bm = blockIdx.y, bn = blockIdx.x;
  int tid = threadIdx.x;
  int wid = tid >> 6, lane = tid & 63;
  int lm = lane & 15, lq = lane >> 4;
  int wm = (wid >> 1) * 64, wn = (wid & 1) * 64;

  __shared__ u16 As[128 * 32];
  __shared__ u16 Bs[128 * 32];

  f32x4 acc[4][4];
#pragma unroll
  for (int i = 0; i < 4; ++i)
#pragma unroll
    for (int j = 0; j < 4; ++j) acc[i][j] = (f32x4){0.f, 0.f, 0.f, 0.f};

  const u16* Ab = A + (bm * 128) * K;
  const u16* Bb = Bt + (bn * 128) * K;
  int srow = lane >> 2;
  int scol = (lane & 3) * 8;

  for (int k0 = 0; k0 < K; k0 += 32) {
    __syncthreads();
#pragma unroll
    for (int j = 0; j < 2; ++j) {
      int c = wid * 2 + j;
      int row = c * 16 + srow;
      async_copy16(&As[c * 512], Ab + row * K + k0 + scol);
      async_copy16(&Bs[c * 512], Bb + row * K + k0 + scol);
    }
    __syncthreads();
    bf16x8 af[4], bf[4];
#pragma unroll
    for (int mt = 0; mt < 4; ++mt)
      af[mt] = *reinterpret_cast<const bf16x8*>(&As[(wm + mt * 16 + lm) * 32 + lq * 8]);
#pragma unroll
    for (int nt = 0; nt < 4; ++nt)
      bf[nt] = *reinterpret_cast<const bf16x8*>(&Bs[(wn + nt * 16 + lm) * 32 + lq * 8]);
#pragma unroll
    for (int mt = 0; mt < 4; ++mt)
#pragma unroll
      for (int nt = 0; nt < 4; ++nt)
        acc[mt][nt] = __builtin_amdgcn_mfma_f32_16x16x32_bf16(af[mt], bf[nt], acc[mt][nt], 0, 0, 0);
  }

#pragma unroll
  for (int mt = 0; mt < 4; ++mt) {
#pragma unroll
    for (int nt = 0; nt < 4; ++nt) {
#pragma unroll
      for (int r = 0; r < 4; ++r) {
        int m = bm * 128 + wm + mt * 16 + lq * 4 + r;
        int n = bn * 128 + wn + nt * 16 + lm;
        out[m * N + n] = acc[mt][nt][r] + b_proj[n];
      }
    }
  }
}

extern "C" void kernel_launch(void* const* d_in, const int* in_sizes, int n_in,
                              void* d_out, int out_size, void* d_ws, size_t ws_size,
                              hipStream_t stream) {
  const float* x      = (const float*)d_in[0];
  const float* W_attn = (const float*)d_in[1];
  const float* b_attn = (const float*)d_in[2];
  const float* bQ     = (const float*)d_in[3];
  const float* bK     = (const float*)d_in[4];
  const float* W_proj = (const float*)d_in[5];
  const float* b_proj = (const float*)d_in[6];
  float* out = (float*)d_out;

  char* ws = (char*)d_ws;
  u16* xb  = (u16*)(ws);                              // [8192][1024]      16 MB
  u16* WaT = (u16*)(ws + 16777216);                   // [3072][1024]       6 MB
  u16* WpT = (u16*)(ws + 23068672);                   // [1024][1024]       2 MB
  u16* qw  = (u16*)(ws + 25165824);                   // [B,NH,T,D] scaled 16 MB
  u16* kw  = (u16*)(ws + 41943040);                   // [B,NH,T,D]        16 MB
  u16* vw  = (u16*)(ws + 58720256);                   // [B,NH,D,T] (V^T)  16 MB
  u16* yw  = (u16*)(ws + 75497472);                   // [8192][1024]      16 MB

  conv_bf16<<<M_ * C_ / (4 * 256), 256, 0, stream>>>(x, xb, M_ * C_);
  {
    dim3 g(N_QKV / 32, C_ / 32);
    transpose_bf16<<<g, 256, 0, stream>>>(W_attn, WaT, C_, N_QKV);
  }
  {
    dim3 g(C_ / 32, C_ / 32);
    transpose_bf16<<<g, 256, 0, stream>>>(W_proj, WpT, C_, C_);
  }
  {
    dim3 g(N_QKV / 128, M_ / 128);  // (24, 64)
    gemm_qkv<<<g, 256, 0, stream>>>(xb, WaT, b_attn, bQ, bK, qw, kw, vw);
  }
  attn_kernel<<<ATTN_BLOCKS, 256, 0, stream>>>(qw, kw, vw, yw);
  {
    dim3 g(C_ / 128, M_ / 128);     // (8, 64)
    gemm_proj<<<g, 256, 0, stream>>>(yw, WpT, b_proj, out);
  }
}

// Round 2
// 313.882 us; speedup vs baseline: 1.1330x; 1.0099x over previous
//
#include <hip/hip_runtime.h>

typedef unsigned short u16;
typedef unsigned int u32;
typedef __bf16 bf16x8 __attribute__((ext_vector_type(8)));
typedef float f32x4 __attribute__((ext_vector_type(4)));

#define B_  4
#define T_  2048
#define C_  1024
#define NH_ 16
#define D_  64
#define M_  (B_*T_)          // 8192
#define N_QKV (3*C_)         // 3072

#define ATTN_BLOCKS 1024     // one block per item, 4 blocks/CU (32KB LDS)

// raw barrier + static waitcnt (no vmcnt(0) drain -- keeps prefetch in flight)
#define BARRIER()  __asm__ __volatile__("s_barrier" ::: "memory")
#define WAIT_VM4() __asm__ __volatile__("s_waitcnt vmcnt(4)" ::: "memory")
#define WAIT_VM0() __asm__ __volatile__("s_waitcnt vmcnt(0)" ::: "memory")
#define LGKM0()    __asm__ __volatile__("s_waitcnt lgkmcnt(0)" ::: "memory")

// async global->LDS, 16B per lane. LDS dest = wave-uniform base + lane*16
__device__ __forceinline__ void async_copy16(void* lds, const void* gptr) {
  __builtin_amdgcn_global_load_lds(
      (const __attribute__((address_space(1))) u32*)gptr,
      (__attribute__((address_space(3))) u32*)(u32)(uintptr_t)lds,
      16, 0, 0);
}

// RNE float -> bf16 bits
__device__ __forceinline__ u16 f2bf(float f) {
  union { float f; unsigned u; } c; c.f = f;
  unsigned u = c.u;
  unsigned r = (u + 0x7fffu + ((u >> 16) & 1u)) >> 16;
  return (u16)r;
}

// ---------------- elementwise fp32 -> bf16 ----------------
__global__ __launch_bounds__(256) void conv_bf16(const float* __restrict__ in,
                                                 u16* __restrict__ out, int n) {
  int i = (blockIdx.x * 256 + threadIdx.x) * 4;
  if (i < n) {
    float4 f = *reinterpret_cast<const float4*>(in + i);
    u16 o[4] = { f2bf(f.x), f2bf(f.y), f2bf(f.z), f2bf(f.w) };
    *reinterpret_cast<uint2*>(out + i) = *reinterpret_cast<uint2*>(o);
  }
}

// ---------------- transpose fp32 [K][N] -> bf16 [N][K] ----------------
__global__ __launch_bounds__(256) void transpose_bf16(const float* __restrict__ in,
                                                      u16* __restrict__ out,
                                                      int K, int N) {
  __shared__ float tile[32][33];
  int bi = blockIdx.y;
  int bj = blockIdx.x;
  int tx = threadIdx.x & 31;
  int ty = threadIdx.x >> 5;
#pragma unroll
  for (int i = 0; i < 4; ++i) {
    int row = ty + i * 8;
    tile[row][tx] = in[(bi * 32 + row) * N + bj * 32 + tx];
  }
  __syncthreads();
#pragma unroll
  for (int i = 0; i < 4; ++i) {
    int row = ty + i * 8;
    out[(bj * 32 + row) * K + bi * 32 + tx] = f2bf(tile[tx][row]);
  }
}

// ---------------- QKV GEMM: 256x256 8-phase (T2+T3+T4+T5) ----------------
// 512 thr = 8 waves (2M x 4N), per-wave C = 128x64 (acc 8x4 fp32x4 = 128 VGPR).
// BK=64, LDS = 2 buf x (A 256x64 + B 256x64) bf16 = 128 KB, 1 block/CU.
// Stage unit = half-tile (128 rows x 64 k) = 2 global_load_lds/wave.
// Per-tile phases P1..P4 (quadrants of C, 16 MFMA each):
//   P1: ds_read B(all 8) + A-low(8) | stage B.h0(next) | bar | lgkm0 | prio1 16mfma prio0 | bar
//   P2: ds_read A-high(8)           | stage B.h1(next) | bar | lgkm0 | prio1 16mfma prio0 | bar
//   P3:                             | stage A.h0(next2)| bar |        prio1 16mfma prio0 | bar
//   P4:                             | stage A.h1(next2)| vmcnt(4) bar | prio1 16mfma prio0 | bar
// FIFO proof: at P4's vmcnt(4) the 2 newest half-tiles (4 loads) stay in
// flight; the 8 older loads = the tile read next phase-group, fully landed.
// buf re-use proof: buf reads are all issued P1/P2 and drained by that
// phase's lgkmcnt(0) before its end barrier => stages into that buf from the
// 3rd phase onward cannot race.
// Swizzle (both sides, same involution): staged with global col-group
// (l&7)^(l>>3); ds_read col-group (kh*4+lq)^(lm&7) -> 8 consecutive lanes hit
// 8 distinct bank quads (conflict-free b128).
__global__ __launch_bounds__(512, 2) void gemm_qkv(const u16* __restrict__ A,
                                                   const u16* __restrict__ Bt,
                                                   const float* __restrict__ b_attn,
                                                   const float* __restrict__ bQ,
                                                   const float* __restrict__ bK,
                                                   u16* __restrict__ qo,
                                                   u16* __restrict__ ko,
                                                   u16* __restrict__ vo) {
  const int K = C_;
  const int NT = K / 64;           // 16 K-tiles
  // bijective XCD swizzle: 384 blocks = 8 XCDs x 48; bm-major within an XCD
  // chunk -> 4 A-panels (2 MB) resident in that XCD's L2 across 12 bn.
  int bid = blockIdx.x;
  int wg = (bid & 7) * 48 + (bid >> 3);
  int bm = wg / 12, bn = wg % 12;

  int tid = threadIdx.x;
  int w = tid >> 6, lane = tid & 63;
  int lm = lane & 15, lq = lane >> 4;
  int wr = w >> 2, wc = w & 3;     // wave grid 2M x 4N

  __shared__ u16 As[2][256 * 64];  // 64 KB
  __shared__ u16 Bs[2][256 * 64];  // 64 KB

  const u16* Ab = A + (size_t)(bm * 256) * K;
  const u16* Bb = Bt + (size_t)(bn * 256) * K;
  int srow = lane >> 3;                  // row within 8-row group
  int sgc  = ((lane & 7) ^ srow) * 8;    // pre-swizzled global u16 col offset

  auto stageA = [&](int bb, int h, int t) {
#pragma unroll
    for (int j = 0; j < 2; ++j)
      async_copy16(&As[bb][h * 8192 + j * 4096 + w * 512],
                   Ab + (size_t)(h * 128 + j * 64 + w * 8 + srow) * K + t * 64 + sgc);
  };
  auto stageB = [&](int bb, int h, int t) {
#pragma unroll
    for (int j = 0; j < 2; ++j)
      async_copy16(&Bs[bb][h * 8192 + j * 4096 + w * 512],
                   Bb + (size_t)(h * 128 + j * 64 + w * 8 + srow) * K + t * 64 + sgc);
  };

  f32x4 acc[8][4];
#pragma unroll
  for (int i = 0; i < 8; ++i)
#pragma unroll
    for (int j = 0; j < 4; ++j) acc[i][j] = (f32x4){0.f, 0.f, 0.f, 0.f};

  auto readA4 = [&](bf16x8 (&af)[4][2], int bb, int mh) {
#pragma unroll
    for (int mf = 0; mf < 4; ++mf) {
      const u16* base = &As[bb][(wr * 128 + (mh * 4 + mf) * 16 + lm) * 64];
#pragma unroll
      for (int kh = 0; kh < 2; ++kh)
        af[mf][kh] = *reinterpret_cast<const bf16x8*>(base + (((kh * 4 + lq) ^ (lm & 7)) * 8));
    }
  };
  auto readB8 = [&](bf16x8 (&bf)[4][2], int bb) {
#pragma unroll
    for (int nf = 0; nf < 4; ++nf) {
      const u16* base = &Bs[bb][(wc * 64 + nf * 16 + lm) * 64];
#pragma unroll
      for (int kh = 0; kh < 2; ++kh)
        bf[nf][kh] = *reinterpret_cast<const bf16x8*>(base + (((kh * 4 + lq) ^ (lm & 7)) * 8));
    }
  };
  auto quad = [&](bf16x8 (&af)[4][2], bf16x8 (&bf)[4][2], int mb, int nb) {
#pragma unroll
    for (int mf = 0; mf < 4; ++mf)
#pragma unroll
      for (int nf = 0; nf < 2; ++nf)
#pragma unroll
        for (int kh = 0; kh < 2; ++kh)
          acc[mb + mf][nb + nf] = __builtin_amdgcn_mfma_f32_16x16x32_bf16(
              af[mf][kh], bf[nb + nf][kh], acc[mb + mf][nb + nf], 0, 0, 0);
  };

  // process one K-tile (4 phases) from buf bb; stages B halves of tile tbx
  // into buf bbx (P1,P2) and A halves of tile tay into buf bay (P3,P4).
  auto process = [&](int bb, int tbx, int bbx, int tay, int bay) {
    bf16x8 bfr[4][2], aflo[4][2], afhi[4][2];
    // P1
    readB8(bfr, bb);
    readA4(aflo, bb, 0);
    stageB(bbx, 0, tbx);
    BARRIER(); LGKM0();
    __builtin_amdgcn_s_setprio(1); quad(aflo, bfr, 0, 0); __builtin_amdgcn_s_setprio(0);
    BARRIER();
    // P2
    readA4(afhi, bb, 1);
    stageB(bbx, 1, tbx);
    BARRIER(); LGKM0();
    __builtin_amdgcn_s_setprio(1); quad(aflo, bfr, 0, 2); __builtin_amdgcn_s_setprio(0);
    BARRIER();
    // P3
    stageA(bay, 0, tay);
    BARRIER();
    __builtin_amdgcn_s_setprio(1); quad(afhi, bfr, 4, 0); __builtin_amdgcn_s_setprio(0);
    BARRIER();
    // P4
    stageA(bay, 1, tay);
    WAIT_VM4();
    BARRIER();
    __builtin_amdgcn_s_setprio(1); quad(afhi, bfr, 4, 2); __builtin_amdgcn_s_setprio(0);
    BARRIER();
  };

  // prologue: T0 fully (A0,A1,B0,B1) + T1 A-halves; wait T0 (2 units in flight)
  stageA(0, 0, 0); stageA(0, 1, 0); stageB(0, 0, 0); stageB(0, 1, 0);
  stageA(1, 0, 1); stageA(1, 1, 1);
  WAIT_VM4();
  BARRIER();

  for (int i = 0; i < NT / 2; ++i) {
    int t0 = 2 * i, t1 = t0 + 1;
    int s2 = (t0 + 2 < NT) ? t0 + 2 : NT - 1;   // clamped restage keeps
    int s3 = (t0 + 3 < NT) ? t0 + 3 : NT - 1;   // vmcnt counts static
    process(0, t1, 1, s2, 0);   // tile t0 from buf0
    process(1, s2, 0, s3, 1);   // tile t1 from buf1
  }
  WAIT_VM0();   // drain clamped tail prefetches

  // epilogue: sel uniform per block (bn 0-3 -> Q, 4-7 -> K, 8-11 -> V)
  const float qscale = 0.18033688011112042f;  // 1/sqrt(64) * log2(e)
  int sel = bn >> 2;
#pragma unroll
  for (int mf = 0; mf < 8; ++mf) {
#pragma unroll
    for (int nf = 0; nf < 4; ++nf) {
      int n = bn * 256 + wc * 64 + nf * 16 + lm;
      float bias = b_attn[n];
      int c = n & 1023;
      int h = c >> 6;
      int d = c & 63;
      int m0 = bm * 256 + wr * 128 + mf * 16 + lq * 4;
      int b = m0 >> 11;
      int t = m0 & 2047;
      if (sel == 0) {
        float qb = bQ[c];
#pragma unroll
        for (int r = 0; r < 4; ++r)
          qo[(((size_t)(b * NH_ + h) * T_) + t + r) * D_ + d] =
              f2bf((acc[mf][nf][r] + bias + qb) * qscale);
      } else if (sel == 1) {
        float kb2 = bK[c];
#pragma unroll
        for (int r = 0; r < 4; ++r)
          ko[(((size_t)(b * NH_ + h) * T_) + t + r) * D_ + d] =
              f2bf(acc[mf][nf][r] + bias + kb2);
      } else {
        u16 wb[4];
#pragma unroll
        for (int r = 0; r < 4; ++r) wb[r] = f2bf(acc[mf][nf][r] + bias);
        *reinterpret_cast<uint2*>(&vo[((size_t)(b * NH_ + h) * D_ + d) * T_ + t]) =
            *reinterpret_cast<uint2*>(wb);   // V^T: 4 consecutive t -> 8B store
      }
    }
  }
}

// ---------------- Flash attention (unchanged from R1) ----------------
__global__ __launch_bounds__(256, 4) void attn_kernel(const u16* __restrict__ q,
                                                      const u16* __restrict__ k,
                                                      const u16* __restrict__ vt,
                                                      u16* __restrict__ y) {
  int tid = threadIdx.x;
  int w = tid >> 6, lane = tid & 63;
  int lm = lane & 15, lq = lane >> 4;

  __shared__ u16 Ks[2][64 * 64];   // [buf][key][d swizzled]    16 KB
  __shared__ u16 Vs[2][64 * 64];   // [buf][d][key swizzled]    16 KB

  int srow = lane >> 3;            // staging row within 8-row chunk
  int sg   = (lane & 7) ^ srow;    // swizzled 16B col-group

  // static balanced mapping (LPT)
  int idx = blockIdx.x;
  int c8 = idx & 255, jq = idx >> 8;
  int a = c8 & 7, gq = c8 >> 3;
  int qt, bh;
  if (jq == 0)      { qt = 15 - a; bh = gq; }
  else if (jq == 1) { qt = 8 + a;  bh = 32 + gq; }
  else if (jq == 2) { qt = 7 - a;  bh = gq; }
  else              { qt = a;      bh = 32 + gq; }

  int b = bh >> 4, h = bh & 15;
  const int klast = 2 * qt + 1;
  const int qrow0 = qt * 128 + w * 32;

  const u16* qb = q + ((size_t)bh * T_ + qrow0) * D_;
  const u16* kb = k + (size_t)bh * T_ * D_;
  const u16* vb = vt + (size_t)bh * D_ * T_;   // [d][t]

  auto stage_K = [&](int buf, int kbi) {
    const u16* gb = kb + (size_t)(kbi * 64) * 64;
#pragma unroll
    for (int j = 0; j < 2; ++j) {
      int c = w * 2 + j;
      async_copy16(&Ks[buf][c * 512], gb + (c * 8 + srow) * 64 + sg * 8);
    }
  };
  auto stage_V = [&](int buf, int kbi) {
    const u16* gb = vb + kbi * 64;
#pragma unroll
    for (int j = 0; j < 2; ++j) {
      int c = w * 2 + j;
      async_copy16(&Vs[buf][c * 512], gb + (size_t)(c * 8 + srow) * T_ + sg * 8);
    }
  };

  bf16x8 bq[2][2];
#pragma unroll
  for (int qt2 = 0; qt2 < 2; ++qt2) {
    const u16* qp = qb + (qt2 * 16 + lm) * D_ + lq * 8;
    bq[qt2][0] = *reinterpret_cast<const bf16x8*>(qp);
    bq[qt2][1] = *reinterpret_cast<const bf16x8*>(qp + 32);
  }

  f32x4 o[4][2];
#pragma unroll
  for (int dt = 0; dt < 4; ++dt)
#pragma unroll
    for (int qt2 = 0; qt2 < 2; ++qt2) o[dt][qt2] = (f32x4){0.f, 0.f, 0.f, 0.f};
  float mprev[2] = {-1e30f, -1e30f}, lsum[2] = {0.f, 0.f};

  stage_K(0, 0); stage_V(0, 0);
  stage_K(1, 1); stage_V(1, 1);

  for (int kbi = 0; kbi <= klast; ++kbi) {
    int buf = kbi & 1;
    WAIT_VM4();
    BARRIER();

    bf16x8 kf[4][2];
#pragma unroll
    for (int kt = 0; kt < 4; ++kt) {
      const u16* base = &Ks[buf][(kt * 16 + lm) * 64];
      kf[kt][0] = *reinterpret_cast<const bf16x8*>(base + ((lq ^ (lm & 7)) * 8));
      kf[kt][1] = *reinterpret_cast<const bf16x8*>(base + (((4 + lq) ^ (lm & 7)) * 8));
    }

    f32x4 s[4][2];
#pragma unroll
    for (int kt = 0; kt < 4; ++kt)
#pragma unroll
      for (int qt2 = 0; qt2 < 2; ++qt2) {
        f32x4 z = (f32x4){0.f, 0.f, 0.f, 0.f};
        z = __builtin_amdgcn_mfma_f32_16x16x32_bf16(kf[kt][0], bq[qt2][0], z, 0, 0, 0);
        z = __builtin_amdgcn_mfma_f32_16x16x32_bf16(kf[kt][1], bq[qt2][1], z, 0, 0, 0);
        s[kt][qt2] = z;
      }

    bool maskt = (kbi * 64 + 63 > qrow0);
    bf16x8 pb[2][2];
#pragma unroll
    for (int qt2 = 0; qt2 < 2; ++qt2) {
      int qg = qrow0 + qt2 * 16 + lm;
      if (maskt) {
#pragma unroll
        for (int kt = 0; kt < 4; ++kt)
#pragma unroll
          for (int r = 0; r < 4; ++r) {
            int key = kbi * 64 + kt * 16 + lq * 4 + r;
            if (key > qg) s[kt][qt2][r] = -1e30f;
          }
      }
      float mx[4];
#pragma unroll
      for (int kt = 0; kt < 4; ++kt)
        mx[kt] = fmaxf(fmaxf(s[kt][qt2][0], s[kt][qt2][1]),
                       fmaxf(s[kt][qt2][2], s[kt][qt2][3]));
      float mval = fmaxf(fmaxf(mx[0], mx[1]), fmaxf(mx[2], mx[3]));
      mval = fmaxf(mval, __shfl_xor(mval, 16));
      mval = fmaxf(mval, __shfl_xor(mval, 32));
      float mold = mprev[qt2];
      float mnew = fmaxf(mold, mval);
      unsigned long long upd = __ballot(mval > mold);
      if (upd) {
        float alpha = __builtin_exp2f(mold - mnew);
        lsum[qt2] *= alpha;
#pragma unroll
        for (int dt = 0; dt < 4; ++dt) o[dt][qt2] *= alpha;
        mprev[qt2] = mnew;
      }
      float rs = 0.f;
      unsigned pw[8];
#pragma unroll
      for (int kt = 0; kt < 4; ++kt) {
        unsigned pu[4];
#pragma unroll
        for (int r = 0; r < 4; ++r) {
          float p = __builtin_exp2f(s[kt][qt2][r] - mnew);
          rs += p;
          union { float f; unsigned u; } cc; cc.f = p;
          pu[r] = cc.u;
        }
        pw[kt * 2]     = __builtin_amdgcn_perm(pu[1], pu[0], 0x07060302u);
        pw[kt * 2 + 1] = __builtin_amdgcn_perm(pu[3], pu[2], 0x07060302u);
      }
      rs += __shfl_xor(rs, 16);
      rs += __shfl_xor(rs, 32);
      lsum[qt2] += rs;
      union { unsigned u[4]; bf16x8 v; } b0, b1;
#pragma unroll
      for (int t = 0; t < 4; ++t) { b0.u[t] = pw[t]; b1.u[t] = pw[4 + t]; }
      pb[qt2][0] = b0.v;
      pb[qt2][1] = b1.v;
    }

    {
      int r7 = lm & 7;
      int h4 = (lq & 1) * 4;
      int g0 = lq >> 1;
#pragma unroll
      for (int dt = 0; dt < 4; ++dt) {
        const u16* vbase = &Vs[buf][(dt * 16 + lm) * 64];
        union { unsigned long long qd[2]; bf16x8 v; } t0, t1;
        t0.qd[0] = *reinterpret_cast<const unsigned long long*>(vbase + ((g0 ^ r7) * 8) + h4);
        t0.qd[1] = *reinterpret_cast<const unsigned long long*>(vbase + (((g0 + 2) ^ r7) * 8) + h4);
        t1.qd[0] = *reinterpret_cast<const unsigned long long*>(vbase + (((g0 + 4) ^ r7) * 8) + h4);
        t1.qd[1] = *reinterpret_cast<const unsigned long long*>(vbase + (((g0 + 6) ^ r7) * 8) + h4);
#pragma unroll
        for (int qt2 = 0; qt2 < 2; ++qt2) {
          o[dt][qt2] = __builtin_amdgcn_mfma_f32_16x16x32_bf16(t0.v, pb[qt2][0], o[dt][qt2], 0, 0, 0);
          o[dt][qt2] = __builtin_amdgcn_mfma_f32_16x16x32_bf16(t1.v, pb[qt2][1], o[dt][qt2], 0, 0, 0);
        }
      }
    }

    BARRIER();
    int nk = (kbi + 2 <= klast) ? kbi + 2 : klast;
    stage_K(buf, nk); stage_V(buf, nk);
  }

  WAIT_VM0();

#pragma unroll
  for (int qt2 = 0; qt2 < 2; ++qt2) {
    float inv = 1.f / lsum[qt2];
    int qg = qrow0 + qt2 * 16 + lm;
#pragma unroll
    for (int dt = 0; dt < 4; ++dt) {
      u16 wb[4];
#pragma unroll
      for (int r = 0; r < 4; ++r) wb[r] = f2bf(o[dt][qt2][r] * inv);
      int d = dt * 16 + lq * 4;
      *reinterpret_cast<uint2*>(&y[((size_t)(b * T_ + qg) * NH_ + h) * D_ + d]) =
          *reinterpret_cast<uint2*>(wb);
    }
  }
}

// ---------------- Proj GEMM (2-phase with prefetch: T3-minimum) ----------------
__global__ __launch_bounds__(256) void gemm_proj(const u16* __restrict__ A,
                                                 const u16* __restrict__ Bt,
                                                 const float* __restrict__ b_proj,
                                                 float* __restrict__ out) {
  const int K = C_, N = C_;
  int bm = blockIdx.y, bn = blockIdx.x;
  int tid = threadIdx.x;
  int wid = tid >> 6, lane = tid & 63;
  int lm = lane & 15, lq = lane >> 4;
  int wm = (wid >> 1) * 64, wn = (wid & 1) * 64;

  __shared__ u16 As[2][128 * 32];
  __shared__ u16 Bs[2][128 * 32];

  f32x4 acc[4][4];
#pragma unroll
  for (int i = 0; i < 4; ++i)
#pragma unroll
    for (int j = 0; j < 4; ++j) acc[i][j] = (f32x4){0.f, 0.f, 0.f, 0.f};

  const u16* Ab = A + (bm * 128) * K;
  const u16* Bb = Bt + (bn * 128) * K;
  int srow = lane >> 2;
  int scol = (lane & 3) * 8;

  auto stage = [&](int bb, int k0) {
#pragma unroll
    for (int j = 0; j < 2; ++j) {
      int c = wid * 2 + j;
      int row = c * 16 + srow;
      async_copy16(&As[bb][c * 512], Ab + row * K + k0 + scol);
      async_copy16(&Bs[bb][c * 512], Bb + row * K + k0 + scol);
    }
  };

  stage(0, 0);
  const int NTp = K / 32;   // 32
  for (int t = 0; t < NTp; ++t) {
    int bb = t & 1;
    int k1 = (t + 1 < NTp) ? (t + 1) * 32 : t * 32;   // clamp keeps counts static
    stage(bb ^ 1, k1);      // prefetch next tile (hides under this tile's MFMA)
    WAIT_VM4();             // this tile's 4 loads landed; next tile's 4 in flight
    BARRIER();
    bf16x8 af[4], bf[4];
#pragma unroll
    for (int mt = 0; mt < 4; ++mt)
      af[mt] = *reinterpret_cast<const bf16x8*>(&As[bb][(wm + mt * 16 + lm) * 32 + lq * 8]);
#pragma unroll
    for (int nt = 0; nt < 4; ++nt)
      bf[nt] = *reinterpret_cast<const bf16x8*>(&Bs[bb][(wn + nt * 16 + lm) * 32 + lq * 8]);
#pragma unroll
    for (int mt = 0; mt < 4; ++mt)
#pragma unroll
      for (int nt = 0; nt < 4; ++nt)
        acc[mt][nt] = __builtin_amdgcn_mfma_f32_16x16x32_bf16(af[mt], bf[nt], acc[mt][nt], 0, 0, 0);
    LGKM0();                // all reads of buf bb complete before...
    BARRIER();              // ...any wave overwrites it next iteration
  }
  WAIT_VM0();

#pragma unroll
  for (int mt = 0; mt < 4; ++mt) {
#pragma unroll
    for (int nt = 0; nt < 4; ++nt) {
#pragma unroll
      for (int r = 0; r < 4; ++r) {
        int m = bm * 128 + wm + mt * 16 + lq * 4 + r;
        int n = bn * 128 + wn + nt * 16 + lm;
        out[m * N + n] = acc[mt][nt][r] + b_proj[n];
      }
    }
  }
}

extern "C" void kernel_launch(void* const* d_in, const int* in_sizes, int n_in,
                              void* d_out, int out_size, void* d_ws, size_t ws_size,
                              hipStream_t stream) {
  const float* x      = (const float*)d_in[0];
  const float* W_attn = (const float*)d_in[1];
  const float* b_attn = (const float*)d_in[2];
  const float* bQ     = (const float*)d_in[3];
  const float* bK     = (const float*)d_in[4];
  const float* W_proj = (const float*)d_in[5];
  const float* b_proj = (const float*)d_in[6];
  float* out = (float*)d_out;

  char* ws = (char*)d_ws;
  u16* xb  = (u16*)(ws);                              // [8192][1024]      16 MB
  u16* WaT = (u16*)(ws + 16777216);                   // [3072][1024]       6 MB
  u16* WpT = (u16*)(ws + 23068672);                   // [1024][1024]       2 MB
  u16* qw  = (u16*)(ws + 25165824);                   // [B,NH,T,D] scaled 16 MB
  u16* kw  = (u16*)(ws + 41943040);                   // [B,NH,T,D]        16 MB
  u16* vw  = (u16*)(ws + 58720256);                   // [B,NH,D,T] (V^T)  16 MB
  u16* yw  = (u16*)(ws + 75497472);                   // [8192][1024]      16 MB

  conv_bf16<<<M_ * C_ / (4 * 256), 256, 0, stream>>>(x, xb, M_ * C_);
  {
    dim3 g(N_QKV / 32, C_ / 32);
    transpose_bf16<<<g, 256, 0, stream>>>(W_attn, WaT, C_, N_QKV);
  }
  {
    dim3 g(C_ / 32, C_ / 32);
    transpose_bf16<<<g, 256, 0, stream>>>(W_proj, WpT, C_, C_);
  }
  gemm_qkv<<<(M_ / 256) * (N_QKV / 256), 512, 0, stream>>>(xb, WaT, b_attn, bQ, bK, qw, kw, vw);
  attn_kernel<<<ATTN_BLOCKS, 256, 0, stream>>>(qw, kw, vw, yw);
  {
    dim3 g(C_ / 128, M_ / 128);     // (8, 64)
    gemm_proj<<<g, 256, 0, stream>>>(yw, WpT, b_proj, out);
  }
}